// Round 6
// baseline (334.036 us; speedup 1.0000x reference)
//
#include <hip/hip_runtime.h>
#include <hip/hip_bf16.h>

using bf16 = __hip_bfloat16;
typedef unsigned short ushort_t;
typedef unsigned int uint_t;

constexpr int B = 2, T = 200;
constexpr int N0 = 2048, N1 = 512, N2 = 128, N3 = 64;
constexpr int E0 = 16384, E1 = 8192, E2 = 2048;

typedef __attribute__((ext_vector_type(8))) short bf16x8;
typedef __attribute__((ext_vector_type(4))) float f32x4;

// ---- workspace byte offsets (shared host/device) ----
constexpr size_t O_FLAG = 161792;   // int flag (outside the zeroed 40448-int region)
constexpr size_t O_WC1  = 163840;   // 64 f
constexpr size_t O_BIAS = 164096;   // 304 f: b1@0 b2@16 b3@48 b1h@112 b2h@240
constexpr size_t O_BW0  = 165312;   // 49152 f
constexpr size_t O_BW1  = 361920;   // 24576 f
constexpr size_t O_BW2  = 460224;   // 6144 f
constexpr size_t O_PB1  = 484800;   // 1048576 u16
constexpr size_t O_PB2  = 2581952;  // 65536 u16
constexpr size_t O_PB3  = 2713024;  // 8192 u16
constexpr size_t O_WT2  = 2729408;  // 2048 u16  [O=32][C=64]
constexpr size_t O_WT3  = 2733504;  // 8192 u16  [O=64][C=128]
constexpr size_t O_W1H  = 2749888;  // 8192 u16  [O=128][C=64]
constexpr size_t O_W2H  = 2766272;  // 8192 u16  [O=64][C=128]
constexpr size_t O_AA   = 2785280;  // arena A 13,107,200 B (fp32 hp)
constexpr size_t O_BB   = 15892480; // arena B 26,214,400 B (bf16 h)

__device__ __forceinline__ float ldx(const void* p, long i, int bf) {
  if (bf) {
    uint_t v = (uint_t)(((const ushort_t*)p)[i]) << 16;
    float f; __builtin_memcpy(&f, &v, 4); return f;
  }
  return ((const float*)p)[i];
}
__device__ __forceinline__ void stf(float* p, float v) { *p = v; }
__device__ __forceinline__ void stf(bf16* p, float v) { *p = __float2bfloat16(v); }
__device__ __forceinline__ ushort_t f2bfu(float v) {
  bf16 h = __float2bfloat16(v); ushort_t u; __builtin_memcpy(&u, &h, 2); return u;
}

struct InPtrs {
  const void* ea0; const void* ea1; const void* ea2;
  const void* P01; const void* P12; const void* P23;
  const void* Wk1; const void* Wr1; const void* Wk2; const void* Wr2;
  const void* Wk3; const void* Wr3; const void* W1h; const void* W2h;
  const void* b1; const void* b2; const void* b3; const void* b1h; const void* b2h;
  const void* A1; const void* A2; const void* A3;
};

// ---------- setup0: zero CSR ints (blocks 0..157) + dtype probe (block 158) ----------
__global__ void k_setup0(int* I, const ushort_t* ea) {
  if (blockIdx.x < 158) {
    int i = blockIdx.x * 256 + threadIdx.x;
    I[i] = 0;                      // covers 40448 ints exactly
  } else if (threadIdx.x == 0) {
    int c = 0;
    for (int i = 0; i < 128; ++i) {
      uint_t v = (uint_t)ea[i] << 16;
      float f; __builtin_memcpy(&f, &v, 4);
      if (f >= 0.f && f <= 1.0f) c++;
    }
    *(int*)((char*)I + O_FLAG) = (c >= 120) ? 1 : 0;
  }
}

__device__ __forceinline__ void bw_one(const void* ea, int bf, const void* A,
                                       float* bw, int e) {
  float a0 = ldx(ea, e*3+0, bf), a1 = ldx(ea, e*3+1, bf), a2 = ldx(ea, e*3+2, bf);
  float l0 = a0*ldx(A,0,bf) + a1*ldx(A,3,bf) + a2*ldx(A,6,bf);
  float l1 = a0*ldx(A,1,bf) + a1*ldx(A,4,bf) + a2*ldx(A,7,bf);
  float l2 = a0*ldx(A,2,bf) + a1*ldx(A,5,bf) + a2*ldx(A,8,bf);
  float m = fmaxf(l0, fmaxf(l1, l2));
  float x0 = expf(l0 - m), x1 = expf(l1 - m), x2 = expf(l2 - m);
  float inv = 1.0f / (x0 + x1 + x2);
  bw[e*3+0] = x0*inv; bw[e*3+1] = x1*inv; bw[e*3+2] = x2*inv;
}

// ---------- fat prep kernel: edge softmax, P->bf16, W transposes, params ----------
__global__ void k_prep(InPtrs P, char* base) {
  int bf = *(const int*)(base + O_FLAG);
  int bx = blockIdx.x, tid = threadIdx.x;
  float* bw0 = (float*)(base + O_BW0);
  float* bw1 = (float*)(base + O_BW1);
  float* bw2 = (float*)(base + O_BW2);
  if (bx < 64)        { bw_one(P.ea0, bf, P.A1, bw0, bx*256+tid); return; }
  if (bx < 96)        { bw_one(P.ea1, bf, P.A2, bw1, (bx-64)*256+tid); return; }
  if (bx < 104)       { bw_one(P.ea2, bf, P.A3, bw2, (bx-96)*256+tid); return; }
  if (bx < 4200)      { long i = (long)(bx-104)*256+tid;
                        ((ushort_t*)(base+O_PB1))[i] = f2bfu(ldx(P.P01, i, bf)); return; }
  if (bx < 4456)      { int i = (bx-4200)*256+tid;
                        ((ushort_t*)(base+O_PB2))[i] = f2bfu(ldx(P.P12, i, bf)); return; }
  if (bx < 4488)      { int i = (bx-4456)*256+tid;
                        ((ushort_t*)(base+O_PB3))[i] = f2bfu(ldx(P.P23, i, bf)); return; }
  if (bx < 4496)      { int j = (bx-4488)*256+tid; int o = j>>6, c = j&63;
                        float v = (c<48) ? ldx(P.Wk2, c*32+o, bf) : ldx(P.Wr2, (c-48)*32+o, bf);
                        ((ushort_t*)(base+O_WT2))[j] = f2bfu(v); return; }
  if (bx < 4528)      { int j = (bx-4496)*256+tid; int o = j>>7, c = j&127;
                        float v = (c<96) ? ldx(P.Wk3, c*64+o, bf) : ldx(P.Wr3, (c-96)*64+o, bf);
                        ((ushort_t*)(base+O_WT3))[j] = f2bfu(v); return; }
  if (bx < 4560)      { int j = (bx-4528)*256+tid; int o = j>>6, c = j&63;
                        ((ushort_t*)(base+O_W1H))[j] = f2bfu(ldx(P.W1h, c*128+o, bf)); return; }
  if (bx < 4592)      { int j = (bx-4560)*256+tid; int o = j>>7, c = j&127;
                        ((ushort_t*)(base+O_W2H))[j] = f2bfu(ldx(P.W2h, c*64+o, bf)); return; }
  { // params: wc1 (64) + biases (304)
    int i = (bx-4592)*256+tid;
    if (i < 64) {
      ((float*)(base+O_WC1))[i] = (i<48) ? ldx(P.Wk1, i, bf) : ldx(P.Wr1, i-48, bf);
    } else if (i < 368) {
      int j = i - 64; float v;
      if (j < 16)       v = ldx(P.b1, j, bf);
      else if (j < 48)  v = ldx(P.b2, j-16, bf);
      else if (j < 112) v = ldx(P.b3, j-48, bf);
      else if (j < 240) v = ldx(P.b1h, j-112, bf);
      else              v = ldx(P.b2h, j-240, bf);
      ((float*)(base+O_BIAS))[j] = v;
    }
  }
}

__global__ void k_hist3(const int* d0, const int* d1, const int* d2,
                        int* c0, int* c1, int* c2) {
  int i = blockIdx.x * 256 + threadIdx.x;
  if (i < E0) atomicAdd(&c0[d0[i]], 1);
  if (i < E1) atomicAdd(&c1[d1[i]], 1);
  if (i < E2) atomicAdd(&c2[d2[i]], 1);
}

__global__ void k_scan3(const int* c0, int* o0, int* u0,
                        const int* c1, int* o1, int* u1,
                        const int* c2, int* o2, int* u2) {
  const int* cnt; int* off; int* cur; int N;
  if (blockIdx.x == 0)      { cnt = c0; off = o0; cur = u0; N = N0; }
  else if (blockIdx.x == 1) { cnt = c1; off = o1; cur = u1; N = N1; }
  else                      { cnt = c2; off = o2; cur = u2; N = N2; }
  int tid = threadIdx.x;
  int chunk = (N + 63) >> 6;
  int base = tid * chunk;
  int s = 0;
  for (int j = 0; j < chunk; ++j) { int idx = base + j; if (idx < N) s += cnt[idx]; }
  int pre = s;
  for (int d = 1; d < 64; d <<= 1) {
    int v = __shfl_up(pre, d, 64);
    if (tid >= d) pre += v;
  }
  int run = pre - s;
  for (int j = 0; j < chunk; ++j) {
    int idx = base + j;
    if (idx < N) { off[idx] = run; cur[idx] = run; run += cnt[idx]; }
  }
  if (tid == 63) off[N] = run;
}

__global__ void k_fill3(const int* d0, int* u0, int* e0l,
                        const int* d1, int* u1, int* e1l,
                        const int* d2, int* u2, int* e2l) {
  int i = blockIdx.x * 256 + threadIdx.x;
  if (i < E0) { int p = atomicAdd(&u0[d0[i]], 1); e0l[p] = i; }
  if (i < E1) { int p = atomicAdd(&u1[d1[i]], 1); e1l[p] = i; }
  if (i < E2) { int p = atomicAdd(&u2[d2[i]], 1); e2l[p] = i; }
}

// ---------- fused level-1 gather + channel-mix (Cin=1 -> 16), raw x via ldx ----------
__global__ __launch_bounds__(256) void k_gc1(const void* x, const int* src,
    const int* off, const int* elist, const int* cnt, const float* bw,
    const float* W, const float* bias, bf16* h1, const int* flagp) {
  __shared__ float Wl[64];
  __shared__ float bl[16];
  int tid = threadIdx.x;
  if (tid < 64) Wl[tid] = W[tid];
  if (tid < 16) bl[tid] = bias[tid];
  __syncthreads();
  int bf = *flagp;
  int n = blockIdx.y, b = blockIdx.z;
  int t = tid;
  if (t >= T) return;
  int beg = off[n], end = off[n + 1];
  float a0 = 0.f, a1 = 0.f, a2 = 0.f;
  for (int q = beg; q < end; ++q) {
    int e = elist[q];
    int s = src[e];
    float xv = ldx(x, (long)(b * N0 + s) * T + t, bf);
    a0 += bw[e*3+0] * xv; a1 += bw[e*3+1] * xv; a2 += bw[e*3+2] * xv;
  }
  int c = cnt[n];
  float inv = 1.f / (float)(c > 0 ? c : 1);
  a0 *= inv; a1 *= inv; a2 *= inv;
  float xr = ldx(x, (long)(b * N0 + n) * T + t, bf);
  bf16* op = h1 + ((long)(b * N0 + n) * 16) * T + t;
#pragma unroll
  for (int o = 0; o < 16; ++o) {
    float v = a0 * Wl[o] + a1 * Wl[16 + o] + a2 * Wl[32 + o] + xr * Wl[48 + o] + bl[o];
    v = v > 0.f ? v : (expf(v) - 1.f);
    op[o * T] = __float2bfloat16(v);
  }
}

// ---------- fused gather + MFMA channel-mix (levels 2,3) ----------
// hp fp32 [B][N][CIN][T] -> h bf16 [B][N][O][T];  C=4*CIN
template<int CIN, int CPI, int O>
__global__ __launch_bounds__(256) void k_gcm(const float* hp, const int* src,
    const int* off, const int* elist, const int* cnt, const float* bw,
    const ushort_t* Wt, const float* bias, bf16* h, int N) {
  constexpr int C = 4 * CIN;
  constexpr int KG = C / 8;
  constexpr int MT = O / 16;
  __shared__ __align__(16) ushort_t Ws[O * C];
  __shared__ __align__(16) ushort_t Is[64 * C];
  int tid = threadIdx.x;
  int w = tid >> 6, l = tid & 63;
  int lf = l & 15, quad = l >> 4;
  int t0 = blockIdx.x * 64;
  int n = blockIdx.y, b = blockIdx.z;
  // stage W
  {
    const uint4* Wg = (const uint4*)Wt;
    for (int s = tid; s < O * KG; s += 256) {
      int o = s / KG, kg = s % KG;
      *(uint4*)(Ws + o * C + ((kg ^ (o & 7)) * 8)) = Wg[s];
    }
  }
  // gather into registers
  int tx = tid & 63, iy = tid >> 6;
  int t = t0 + tx;
  bool tok = t < T;
  float acc[3][CPI], xr[CPI];
#pragma unroll
  for (int k = 0; k < 3; ++k)
#pragma unroll
    for (int j = 0; j < CPI; ++j) acc[k][j] = 0.f;
#pragma unroll
  for (int j = 0; j < CPI; ++j) xr[j] = 0.f;
  float inv = 1.f;
  if (tok) {
    int beg = off[n], end = off[n + 1];
    for (int q = beg; q < end; ++q) {
      int e = elist[q];
      int s = src[e];
      float w0 = bw[e*3+0], w1 = bw[e*3+1], w2 = bw[e*3+2];
      const float* xp = hp + ((long)(b * N + s) * CIN) * T + t;
#pragma unroll
      for (int j = 0; j < CPI; ++j) {
        float xv = xp[(iy * CPI + j) * T];
        acc[0][j] += w0 * xv; acc[1][j] += w1 * xv; acc[2][j] += w2 * xv;
      }
    }
    int c = cnt[n];
    inv = 1.f / (float)(c > 0 ? c : 1);
    const float* xs = hp + ((long)(b * N + n) * CIN) * T + t;
#pragma unroll
    for (int j = 0; j < CPI; ++j) xr[j] = xs[(iy * CPI + j) * T];
  }
  // dump z|x into swizzled Is (bf16 scalars)
#pragma unroll
  for (int j = 0; j < CPI; ++j) {
    int i = iy * CPI + j;
#pragma unroll
    for (int k = 0; k < 3; ++k) {
      int c = k * CIN + i;
      Is[tx * C + ((c >> 3) ^ (tx & 7)) * 8 + (c & 7)] = f2bfu(acc[k][j] * inv);
    }
    int c = 3 * CIN + i;
    Is[tx * C + ((c >> 3) ^ (tx & 7)) * 8 + (c & 7)] = f2bfu(xr[j]);
  }
  __syncthreads();
  // MFMA
  f32x4 dacc[MT];
#pragma unroll
  for (int mt = 0; mt < MT; ++mt) dacc[mt] = (f32x4){0.f, 0.f, 0.f, 0.f};
  int tr = w * 16 + lf;
#pragma unroll
  for (int kc = 0; kc < C / 32; ++kc) {
    int kg0 = kc * 4 + quad;
    bf16x8 bfr = *(const bf16x8*)(Is + tr * C + ((kg0 ^ (tr & 7)) * 8));
#pragma unroll
    for (int mt = 0; mt < MT; ++mt) {
      int o = mt * 16 + lf;
      bf16x8 afr = *(const bf16x8*)(Ws + o * C + ((kg0 ^ (o & 7)) * 8));
      dacc[mt] = __builtin_amdgcn_mfma_f32_16x16x32_bf16(afr, bfr, dacc[mt], 0, 0, 0);
    }
  }
  int tg = t0 + w * 16 + lf;
  if (tg < T) {
    long nb = (long)(b * N + n) * O;
#pragma unroll
    for (int mt = 0; mt < MT; ++mt) {
#pragma unroll
      for (int r = 0; r < 4; ++r) {
        int o = mt * 16 + quad * 4 + r;
        float v = dacc[mt][r] + bias[o];
        v = v > 0.f ? v : (expf(v) - 1.f);
        h[(nb + o) * T + tg] = __float2bfloat16(v);
      }
    }
  }
}

// ---------- MFMA pool GEMM: out[b,m,f] = sum_k Pb[m,k] * h[b,k,f] ----------
// BM = 64*WMT, BN = 16*FT
template<int WMT, int FT, typename TOut>
__global__ __launch_bounds__(256) void k_pool_mfma(const ushort_t* Pb, const ushort_t* h,
                                                   TOut* out, int M, int K, int F) {
  constexpr int BM = 64 * WMT;
  constexpr int BN = 16 * FT;
  __shared__ __align__(16) ushort_t As[BM * 64];
  __shared__ __align__(16) ushort_t Bs[BN * 64];
  int tid = threadIdx.x;
  int w = tid >> 6, l = tid & 63;
  int lf = l & 15, quad = l >> 4;
  int f0 = blockIdx.x * BN;
  int m0 = blockIdx.y * BM;
  int b = blockIdx.z;
  f32x4 acc[WMT][FT];
#pragma unroll
  for (int wt = 0; wt < WMT; ++wt)
#pragma unroll
    for (int ft = 0; ft < FT; ++ft) acc[wt][ft] = (f32x4){0.f, 0.f, 0.f, 0.f};

  for (int k0 = 0; k0 < K; k0 += 64) {
#pragma unroll
    for (int it = 0; it < BM / 32; ++it) {
      int cc = tid + 256 * it;
      int m = cc >> 3, kc = cc & 7;
      uint4 v = *(const uint4*)(Pb + (long)(m0 + m) * K + k0 + kc * 8);
      *(uint4*)(As + m * 64 + ((kc ^ (m & 7)) * 8)) = v;
    }
#pragma unroll
    for (int kb = (tid / BN) * 16; kb < 64; kb += (256 / BN) * 16) {
      int f = tid % BN;
      const ushort_t* hp = h + ((long)(b * K + k0 + kb)) * F + f0 + f;
      ushort_t r[16];
#pragma unroll
      for (int i = 0; i < 16; ++i) r[i] = hp[(long)i * F];
      int kc0 = kb >> 3;
      *(uint4*)(Bs + f * 64 + ((kc0 ^ (f & 7)) * 8)) = *(uint4*)&r[0];
      *(uint4*)(Bs + f * 64 + (((kc0 + 1) ^ (f & 7)) * 8)) = *(uint4*)&r[8];
    }
    __syncthreads();
#pragma unroll
    for (int ks = 0; ks < 2; ++ks) {
      int kc = ks * 4 + quad;
      bf16x8 bfr[FT];
#pragma unroll
      for (int ft = 0; ft < FT; ++ft) {
        int fl = ft * 16 + lf;
        bfr[ft] = *(const bf16x8*)(Bs + fl * 64 + ((kc ^ (fl & 7)) * 8));
      }
#pragma unroll
      for (int wt = 0; wt < WMT; ++wt) {
        int ml = wt * 64 + w * 16 + lf;
        bf16x8 afr = *(const bf16x8*)(As + ml * 64 + ((kc ^ (ml & 7)) * 8));
#pragma unroll
        for (int ft = 0; ft < FT; ++ft)
          acc[wt][ft] = __builtin_amdgcn_mfma_f32_16x16x32_bf16(afr, bfr[ft], acc[wt][ft], 0, 0, 0);
      }
    }
    __syncthreads();
  }
#pragma unroll
  for (int wt = 0; wt < WMT; ++wt) {
#pragma unroll
    for (int r = 0; r < 4; ++r) {
      int m = m0 + wt * 64 + w * 16 + quad * 4 + r;
      TOut* op = out + ((long)(b * M + m)) * F + f0 + lf;
#pragma unroll
      for (int ft = 0; ft < FT; ++ft)
        stf(op + ft * 16, acc[wt][ft][r]);
    }
  }
}

// ---------- fused head: hp3 fp32 [B][64][64][T] -> elu(W1) -> tanh(W2) -> d_out ----------
__global__ __launch_bounds__(256) void k_head(const float* hp3, const ushort_t* W1t,
    const ushort_t* W2t, const float* bias, void* outp, const int* flagp) {
  __shared__ __align__(16) ushort_t Ws1[128 * 64];
  __shared__ __align__(16) ushort_t Ws2[64 * 128];
  __shared__ __align__(16) ushort_t Is[64 * 64];
  __shared__ __align__(16) ushort_t G[64 * 128];
  int tid = threadIdx.x;
  int w = tid >> 6, l = tid & 63;
  int lf = l & 15, quad = l >> 4;
  int t0 = blockIdx.x * 64;
  int n = blockIdx.y, b = blockIdx.z;
  // stage W1t [128][64] and W2t [64][128]
  {
    const uint4* g1 = (const uint4*)W1t;
    for (int s = tid; s < 1024; s += 256) {
      int o = s >> 3, kg = s & 7;
      *(uint4*)(Ws1 + o * 64 + ((kg ^ (o & 7)) * 8)) = g1[s];
    }
    const uint4* g2 = (const uint4*)W2t;
    for (int s = tid; s < 1024; s += 256) {
      int o = s >> 4, kg = s & 15;
      *(uint4*)(Ws2 + o * 128 + ((kg ^ (o & 7)) * 8)) = g2[s];
    }
  }
  // stage Is [64t][64c] from hp3
  {
    int t = tid & 63;
    bool tok = (t0 + t) < T;
    const float* ip = hp3 + ((long)(b * 64 + n) * 64) * T + t0;
    for (int kg = tid >> 6; kg < 8; kg += 4) {
      ushort_t r[8];
#pragma unroll
      for (int j = 0; j < 8; ++j)
        r[j] = tok ? f2bfu(ip[(kg * 8 + j) * T + t]) : (ushort_t)0;
      *(uint4*)(Is + t * 64 + ((kg ^ (t & 7)) * 8)) = *(uint4*)r;
    }
  }
  __syncthreads();
  int tr = w * 16 + lf;
  // MFMA1: 64 -> 128, elu, into G
  {
    f32x4 a1[8];
#pragma unroll
    for (int mt = 0; mt < 8; ++mt) a1[mt] = (f32x4){0.f, 0.f, 0.f, 0.f};
#pragma unroll
    for (int kc = 0; kc < 2; ++kc) {
      int kg0 = kc * 4 + quad;
      bf16x8 bfr = *(const bf16x8*)(Is + tr * 64 + ((kg0 ^ (tr & 7)) * 8));
#pragma unroll
      for (int mt = 0; mt < 8; ++mt) {
        int o = mt * 16 + lf;
        bf16x8 afr = *(const bf16x8*)(Ws1 + o * 64 + ((kg0 ^ (o & 7)) * 8));
        a1[mt] = __builtin_amdgcn_mfma_f32_16x16x32_bf16(afr, bfr, a1[mt], 0, 0, 0);
      }
    }
    int tG = w * 16 + lf;
#pragma unroll
    for (int mt = 0; mt < 8; ++mt) {
#pragma unroll
      for (int r = 0; r < 4; ++r) {
        int o1 = mt * 16 + quad * 4 + r;
        float v = a1[mt][r] + bias[112 + o1];
        v = v > 0.f ? v : (expf(v) - 1.f);
        G[tG * 128 + ((o1 >> 3) ^ (tG & 7)) * 8 + (o1 & 7)] = f2bfu(v);
      }
    }
  }
  __syncthreads();
  // MFMA2: 128 -> 64, tanh, store
  {
    f32x4 a2[4];
#pragma unroll
    for (int mt = 0; mt < 4; ++mt) a2[mt] = (f32x4){0.f, 0.f, 0.f, 0.f};
#pragma unroll
    for (int kc = 0; kc < 4; ++kc) {
      int kg0 = kc * 4 + quad;
      bf16x8 bfr = *(const bf16x8*)(G + tr * 128 + ((kg0 ^ (tr & 7)) * 8));
#pragma unroll
      for (int mt = 0; mt < 4; ++mt) {
        int o = mt * 16 + lf;
        bf16x8 afr = *(const bf16x8*)(Ws2 + o * 128 + ((kg0 ^ (o & 7)) * 8));
        a2[mt] = __builtin_amdgcn_mfma_f32_16x16x32_bf16(afr, bfr, a2[mt], 0, 0, 0);
      }
    }
    int t = t0 + w * 16 + lf;
    if (t < T) {
      int bf = *flagp;
      long nb = (long)(b * 64 + n) * 64;
#pragma unroll
      for (int mt = 0; mt < 4; ++mt) {
#pragma unroll
        for (int r = 0; r < 4; ++r) {
          int o2 = mt * 16 + quad * 4 + r;
          float v = tanhf(a2[mt][r] + bias[240 + o2]);
          long idx = (nb + o2) * T + t;
          if (bf) ((bf16*)outp)[idx] = __float2bfloat16(v);
          else    ((float*)outp)[idx] = v;
        }
      }
    }
  }
}

extern "C" void kernel_launch(void* const* d_in, const int* in_sizes, int n_in,
                              void* d_out, int out_size, void* d_ws, size_t ws_size,
                              hipStream_t stream) {
  const int* ei0 = (const int*)d_in[1];
  const int* ei1 = (const int*)d_in[3];
  const int* ei2 = (const int*)d_in[5];

  char* base = (char*)d_ws;
  int* I = (int*)base;
  int* cnt0 = I;         int* off0 = I + 2048;  int* cur0 = I + 4112;  int* el0 = I + 6160;
  int* cnt1 = I + 22544; int* off1 = I + 23056; int* cur1 = I + 23584; int* el1 = I + 24096;
  int* cnt2 = I + 32288; int* off2 = I + 32416; int* cur2 = I + 32560; int* el2 = I + 32688;
  const int* flagp = (const int*)(base + O_FLAG);
  float* wc1f = (float*)(base + O_WC1);
  float* bias = (float*)(base + O_BIAS);
  float* bw0 = (float*)(base + O_BW0);
  float* bw1 = (float*)(base + O_BW1);
  float* bw2 = (float*)(base + O_BW2);
  ushort_t* Pb1 = (ushort_t*)(base + O_PB1);
  ushort_t* Pb2 = (ushort_t*)(base + O_PB2);
  ushort_t* Pb3 = (ushort_t*)(base + O_PB3);
  ushort_t* wt2 = (ushort_t*)(base + O_WT2);
  ushort_t* wt3 = (ushort_t*)(base + O_WT3);
  ushort_t* w1t = (ushort_t*)(base + O_W1H);
  ushort_t* w2t = (ushort_t*)(base + O_W2H);
  char* Aa = base + O_AA;
  char* Bb = base + O_BB;

  InPtrs P = { d_in[2], d_in[4], d_in[6], d_in[19], d_in[20], d_in[21],
               d_in[8], d_in[9], d_in[12], d_in[13], d_in[16], d_in[17],
               d_in[22], d_in[24], d_in[10], d_in[14], d_in[18], d_in[23],
               d_in[25], d_in[7], d_in[11], d_in[15] };

  k_setup0<<<159, 256, 0, stream>>>(I, (const ushort_t*)d_in[2]);
  k_prep<<<4594, 256, 0, stream>>>(P, base);
  k_hist3<<<64, 256, 0, stream>>>(ei0 + E0, ei1 + E1, ei2 + E2, cnt0, cnt1, cnt2);
  k_scan3<<<3, 64, 0, stream>>>(cnt0, off0, cur0, cnt1, off1, cur1, cnt2, off2, cur2);
  k_fill3<<<64, 256, 0, stream>>>(ei0 + E0, cur0, el0, ei1 + E1, cur1, el1, ei2 + E2, cur2, el2);

  // level 0 -> 1: h1 bf16 (Bb), pool1 -> hp1 fp32 (Aa)
  k_gc1<<<dim3(1, N0, B), 256, 0, stream>>>(d_in[0], ei0, off0, el0, cnt0, bw0, wc1f, bias, (bf16*)Bb, flagp);
  k_pool_mfma<2, 8, float><<<dim3(25, 4, B), 256, 0, stream>>>(Pb1, (const ushort_t*)Bb, (float*)Aa, 512, 2048, 3200);
  // level 1 -> 2: fused gather+cmix -> h2 bf16 (Bb), pool2 -> hp2 fp32 (Aa)
  k_gcm<16, 4, 32><<<dim3(4, N1, B), 256, 0, stream>>>((const float*)Aa, ei1, off1, el1, cnt1, bw1, wt2, bias + 16, (bf16*)Bb, N1);
  k_pool_mfma<1, 4, float><<<dim3(100, 2, B), 256, 0, stream>>>(Pb2, (const ushort_t*)Bb, (float*)Aa, 128, 512, 6400);
  // level 2 -> 3: fused gather+cmix -> h3 bf16 (Bb), pool3 -> hp3 fp32 (Aa)
  k_gcm<32, 8, 64><<<dim3(4, N2, B), 256, 0, stream>>>((const float*)Aa, ei2, off2, el2, cnt2, bw2, wt3, bias + 48, (bf16*)Bb, N2);
  k_pool_mfma<1, 4, float><<<dim3(200, 1, B), 256, 0, stream>>>(Pb3, (const ushort_t*)Bb, (float*)Aa, 64, 128, 12800);
  // fused head -> d_out
  k_head<<<dim3(4, N3, B), 256, 0, stream>>>((const float*)Aa, w1t, w2t, bias, d_out, flagp);
}

// Round 7
// 285.712 us; speedup vs baseline: 1.1691x; 1.1691x over previous
//
#include <hip/hip_runtime.h>
#include <hip/hip_bf16.h>

using bf16 = __hip_bfloat16;
typedef unsigned short ushort_t;
typedef unsigned int uint_t;

constexpr int B = 2, T = 200;
constexpr int N0 = 2048, N1 = 512, N2 = 128, N3 = 64;
constexpr int E0 = 16384, E1 = 8192, E2 = 2048;

typedef __attribute__((ext_vector_type(8))) short bf16x8;
typedef __attribute__((ext_vector_type(4))) float f32x4;

// ---- workspace byte offsets (shared host/device) ----
constexpr size_t O_FLAG = 161792;   // int flag (outside the zeroed 40448-int region)
constexpr size_t O_WC1  = 163840;   // 64 f
constexpr size_t O_BIAS = 164096;   // 304 f: b1@0 b2@16 b3@48 b1h@112 b2h@240
constexpr size_t O_BW0  = 165312;   // 49152 f
constexpr size_t O_BW1  = 361920;   // 24576 f
constexpr size_t O_BW2  = 460224;   // 6144 f
constexpr size_t O_PB1  = 484800;   // 1048576 u16
constexpr size_t O_PB2  = 2581952;  // 65536 u16
constexpr size_t O_PB3  = 2713024;  // 8192 u16
constexpr size_t O_WT2  = 2729408;  // 2048 u16  [O=32][C=64]
constexpr size_t O_WT3  = 2733504;  // 8192 u16  [O=64][C=128]
constexpr size_t O_W1H  = 2749888;  // 8192 u16  [O=128][C=64]
constexpr size_t O_W2H  = 2766272;  // 8192 u16  [O=64][C=128]
constexpr size_t O_AA   = 2785280;  // arena A 13,107,200 B (fp32 hp)
constexpr size_t O_BB   = 15892480; // arena B 26,214,400 B (bf16 h)

__device__ __forceinline__ float ldx(const void* p, long i, int bf) {
  if (bf) {
    uint_t v = (uint_t)(((const ushort_t*)p)[i]) << 16;
    float f; __builtin_memcpy(&f, &v, 4); return f;
  }
  return ((const float*)p)[i];
}
__device__ __forceinline__ void stf(float* p, float v) { *p = v; }
__device__ __forceinline__ void stf(bf16* p, float v) { *p = __float2bfloat16(v); }
__device__ __forceinline__ ushort_t f2bfu(float v) {
  bf16 h = __float2bfloat16(v); ushort_t u; __builtin_memcpy(&u, &h, 2); return u;
}

struct InPtrs {
  const void* ea0; const void* ea1; const void* ea2;
  const void* P01; const void* P12; const void* P23;
  const void* Wk1; const void* Wr1; const void* Wk2; const void* Wr2;
  const void* Wk3; const void* Wr3; const void* W1h; const void* W2h;
  const void* b1; const void* b2; const void* b3; const void* b1h; const void* b2h;
  const void* A1; const void* A2; const void* A3;
};

// ---------- setup0: zero CSR ints (blocks 0..157) + dtype probe (block 158) ----------
__global__ void k_setup0(int* I, const ushort_t* ea) {
  if (blockIdx.x < 158) {
    int i = blockIdx.x * 256 + threadIdx.x;
    I[i] = 0;                      // covers 40448 ints exactly
  } else if (threadIdx.x == 0) {
    int c = 0;
    for (int i = 0; i < 128; ++i) {
      uint_t v = (uint_t)ea[i] << 16;
      float f; __builtin_memcpy(&f, &v, 4);
      if (f >= 0.f && f <= 1.0f) c++;
    }
    *(int*)((char*)I + O_FLAG) = (c >= 120) ? 1 : 0;
  }
}

__device__ __forceinline__ void bw_one(const void* ea, int bf, const void* A,
                                       float* bw, int e) {
  float a0 = ldx(ea, e*3+0, bf), a1 = ldx(ea, e*3+1, bf), a2 = ldx(ea, e*3+2, bf);
  float l0 = a0*ldx(A,0,bf) + a1*ldx(A,3,bf) + a2*ldx(A,6,bf);
  float l1 = a0*ldx(A,1,bf) + a1*ldx(A,4,bf) + a2*ldx(A,7,bf);
  float l2 = a0*ldx(A,2,bf) + a1*ldx(A,5,bf) + a2*ldx(A,8,bf);
  float m = fmaxf(l0, fmaxf(l1, l2));
  float x0 = expf(l0 - m), x1 = expf(l1 - m), x2 = expf(l2 - m);
  float inv = 1.0f / (x0 + x1 + x2);
  bw[e*3+0] = x0*inv; bw[e*3+1] = x1*inv; bw[e*3+2] = x2*inv;
}

// ---------- fat prep kernel: edge softmax, P->bf16, W transposes, params ----------
__global__ void k_prep(InPtrs P, char* base) {
  int bf = *(const int*)(base + O_FLAG);
  int bx = blockIdx.x, tid = threadIdx.x;
  float* bw0 = (float*)(base + O_BW0);
  float* bw1 = (float*)(base + O_BW1);
  float* bw2 = (float*)(base + O_BW2);
  if (bx < 64)        { bw_one(P.ea0, bf, P.A1, bw0, bx*256+tid); return; }
  if (bx < 96)        { bw_one(P.ea1, bf, P.A2, bw1, (bx-64)*256+tid); return; }
  if (bx < 104)       { bw_one(P.ea2, bf, P.A3, bw2, (bx-96)*256+tid); return; }
  if (bx < 4200)      { long i = (long)(bx-104)*256+tid;
                        ((ushort_t*)(base+O_PB1))[i] = f2bfu(ldx(P.P01, i, bf)); return; }
  if (bx < 4456)      { int i = (bx-4200)*256+tid;
                        ((ushort_t*)(base+O_PB2))[i] = f2bfu(ldx(P.P12, i, bf)); return; }
  if (bx < 4488)      { int i = (bx-4456)*256+tid;
                        ((ushort_t*)(base+O_PB3))[i] = f2bfu(ldx(P.P23, i, bf)); return; }
  if (bx < 4496)      { int j = (bx-4488)*256+tid; int o = j>>6, c = j&63;
                        float v = (c<48) ? ldx(P.Wk2, c*32+o, bf) : ldx(P.Wr2, (c-48)*32+o, bf);
                        ((ushort_t*)(base+O_WT2))[j] = f2bfu(v); return; }
  if (bx < 4528)      { int j = (bx-4496)*256+tid; int o = j>>7, c = j&127;
                        float v = (c<96) ? ldx(P.Wk3, c*64+o, bf) : ldx(P.Wr3, (c-96)*64+o, bf);
                        ((ushort_t*)(base+O_WT3))[j] = f2bfu(v); return; }
  if (bx < 4560)      { int j = (bx-4528)*256+tid; int o = j>>6, c = j&63;
                        ((ushort_t*)(base+O_W1H))[j] = f2bfu(ldx(P.W1h, c*128+o, bf)); return; }
  if (bx < 4592)      { int j = (bx-4560)*256+tid; int o = j>>7, c = j&127;
                        ((ushort_t*)(base+O_W2H))[j] = f2bfu(ldx(P.W2h, c*64+o, bf)); return; }
  { // params: wc1 (64) + biases (304)
    int i = (bx-4592)*256+tid;
    if (i < 64) {
      ((float*)(base+O_WC1))[i] = (i<48) ? ldx(P.Wk1, i, bf) : ldx(P.Wr1, i-48, bf);
    } else if (i < 368) {
      int j = i - 64; float v;
      if (j < 16)       v = ldx(P.b1, j, bf);
      else if (j < 48)  v = ldx(P.b2, j-16, bf);
      else if (j < 112) v = ldx(P.b3, j-48, bf);
      else if (j < 240) v = ldx(P.b1h, j-112, bf);
      else              v = ldx(P.b2h, j-240, bf);
      ((float*)(base+O_BIAS))[j] = v;
    }
  }
}

__global__ void k_hist3(const int* d0, const int* d1, const int* d2,
                        int* c0, int* c1, int* c2) {
  int i = blockIdx.x * 256 + threadIdx.x;
  if (i < E0) atomicAdd(&c0[d0[i]], 1);
  if (i < E1) atomicAdd(&c1[d1[i]], 1);
  if (i < E2) atomicAdd(&c2[d2[i]], 1);
}

__global__ void k_scan3(const int* c0, int* o0, int* u0,
                        const int* c1, int* o1, int* u1,
                        const int* c2, int* o2, int* u2) {
  const int* cnt; int* off; int* cur; int N;
  if (blockIdx.x == 0)      { cnt = c0; off = o0; cur = u0; N = N0; }
  else if (blockIdx.x == 1) { cnt = c1; off = o1; cur = u1; N = N1; }
  else                      { cnt = c2; off = o2; cur = u2; N = N2; }
  int tid = threadIdx.x;
  int chunk = (N + 63) >> 6;
  int base = tid * chunk;
  int s = 0;
  for (int j = 0; j < chunk; ++j) { int idx = base + j; if (idx < N) s += cnt[idx]; }
  int pre = s;
  for (int d = 1; d < 64; d <<= 1) {
    int v = __shfl_up(pre, d, 64);
    if (tid >= d) pre += v;
  }
  int run = pre - s;
  for (int j = 0; j < chunk; ++j) {
    int idx = base + j;
    if (idx < N) { off[idx] = run; cur[idx] = run; run += cnt[idx]; }
  }
  if (tid == 63) off[N] = run;
}

__global__ void k_fill3(const int* d0, int* u0, int* e0l,
                        const int* d1, int* u1, int* e1l,
                        const int* d2, int* u2, int* e2l) {
  int i = blockIdx.x * 256 + threadIdx.x;
  if (i < E0) { int p = atomicAdd(&u0[d0[i]], 1); e0l[p] = i; }
  if (i < E1) { int p = atomicAdd(&u1[d1[i]], 1); e1l[p] = i; }
  if (i < E2) { int p = atomicAdd(&u2[d2[i]], 1); e2l[p] = i; }
}

// ---------- fused level-1 gather + channel-mix (Cin=1 -> 16), raw x via ldx ----------
// edge data staged in LDS per block (chunks of 32, uniform trip count)
__global__ __launch_bounds__(256) void k_gc1(const void* x, const int* src,
    const int* off, const int* elist, const int* cnt, const float* bw,
    const float* W, const float* bias, bf16* h1, const int* flagp) {
  __shared__ float Wl[64];
  __shared__ float bl[16];
  __shared__ float ew0[32], ew1[32], ew2[32];
  __shared__ int es[32];
  int tid = threadIdx.x;
  if (tid < 64) Wl[tid] = W[tid];
  if (tid < 16) bl[tid] = bias[tid];
  int bf = *flagp;
  int n = blockIdx.y, b = blockIdx.z;
  int t = tid;
  bool tok = t < T;
  int beg = off[n], end = off[n + 1];
  float a0 = 0.f, a1 = 0.f, a2 = 0.f;
  for (int q0 = beg; q0 < end; q0 += 32) {
    int m = end - q0; if (m > 32) m = 32;
    __syncthreads();
    if (tid < m) {
      int e = elist[q0 + tid];
      es[tid] = src[e];
      ew0[tid] = bw[e*3+0]; ew1[tid] = bw[e*3+1]; ew2[tid] = bw[e*3+2];
    }
    __syncthreads();
    if (tok) {
      for (int j = 0; j < m; ++j) {
        float xv = ldx(x, (long)(b * N0 + es[j]) * T + t, bf);
        a0 += ew0[j] * xv; a1 += ew1[j] * xv; a2 += ew2[j] * xv;
      }
    }
  }
  __syncthreads();   // Wl/bl visibility even when the edge loop has 0 iterations
  if (!tok) return;
  int c = cnt[n];
  float inv = 1.f / (float)(c > 0 ? c : 1);
  a0 *= inv; a1 *= inv; a2 *= inv;
  float xr = ldx(x, (long)(b * N0 + n) * T + t, bf);
  bf16* op = h1 + ((long)(b * N0 + n) * 16) * T + t;
#pragma unroll
  for (int o = 0; o < 16; ++o) {
    float v = a0 * Wl[o] + a1 * Wl[16 + o] + a2 * Wl[32 + o] + xr * Wl[48 + o] + bl[o];
    v = v > 0.f ? v : (expf(v) - 1.f);
    op[o * T] = __float2bfloat16(v);
  }
}

// ---------- fused gather + MFMA channel-mix (levels 2,3) ----------
// hp fp32 [B][N][CIN][T] -> h bf16 [B][N][O][T];  C=4*CIN
template<int CIN, int CPI, int O>
__global__ __launch_bounds__(256) void k_gcm(const float* hp, const int* src,
    const int* off, const int* elist, const int* cnt, const float* bw,
    const ushort_t* Wt, const float* bias, bf16* h, int N) {
  constexpr int C = 4 * CIN;
  constexpr int KG = C / 8;
  constexpr int MT = O / 16;
  __shared__ __align__(16) ushort_t Ws[O * C];
  __shared__ __align__(16) ushort_t Is[64 * C];
  __shared__ float ew0[32], ew1[32], ew2[32];
  __shared__ int es[32];
  int tid = threadIdx.x;
  int w = tid >> 6, l = tid & 63;
  int lf = l & 15, quad = l >> 4;
  int t0 = blockIdx.x * 64;
  int n = blockIdx.y, b = blockIdx.z;
  // stage W
  {
    const uint4* Wg = (const uint4*)Wt;
    for (int s = tid; s < O * KG; s += 256) {
      int o = s / KG, kg = s % KG;
      *(uint4*)(Ws + o * C + ((kg ^ (o & 7)) * 8)) = Wg[s];
    }
  }
  // gather into registers, edge data staged in LDS
  int tx = tid & 63, iy = tid >> 6;
  int t = t0 + tx;
  bool tok = t < T;
  float acc[3][CPI], xr[CPI];
#pragma unroll
  for (int k = 0; k < 3; ++k)
#pragma unroll
    for (int j = 0; j < CPI; ++j) acc[k][j] = 0.f;
#pragma unroll
  for (int j = 0; j < CPI; ++j) xr[j] = 0.f;
  int beg = off[n], end = off[n + 1];
  for (int q0 = beg; q0 < end; q0 += 32) {
    int mE = end - q0; if (mE > 32) mE = 32;
    __syncthreads();
    if (tid < mE) {
      int e = elist[q0 + tid];
      es[tid] = src[e];
      ew0[tid] = bw[e*3+0]; ew1[tid] = bw[e*3+1]; ew2[tid] = bw[e*3+2];
    }
    __syncthreads();
    if (tok) {
      for (int j2 = 0; j2 < mE; ++j2) {
        int s = es[j2];
        float w0 = ew0[j2], w1 = ew1[j2], w2 = ew2[j2];
        const float* xp = hp + ((long)(b * N + s) * CIN) * T + t;
#pragma unroll
        for (int j = 0; j < CPI; ++j) {
          float xv = xp[(iy * CPI + j) * T];
          acc[0][j] += w0 * xv; acc[1][j] += w1 * xv; acc[2][j] += w2 * xv;
        }
      }
    }
  }
  float inv = 1.f;
  if (tok) {
    int c = cnt[n];
    inv = 1.f / (float)(c > 0 ? c : 1);
    const float* xs = hp + ((long)(b * N + n) * CIN) * T + t;
#pragma unroll
    for (int j = 0; j < CPI; ++j) xr[j] = xs[(iy * CPI + j) * T];
  }
  // dump z|x into swizzled Is (bf16 scalars)
#pragma unroll
  for (int j = 0; j < CPI; ++j) {
    int i = iy * CPI + j;
#pragma unroll
    for (int k = 0; k < 3; ++k) {
      int c = k * CIN + i;
      Is[tx * C + ((c >> 3) ^ (tx & 7)) * 8 + (c & 7)] = f2bfu(acc[k][j] * inv);
    }
    int c = 3 * CIN + i;
    Is[tx * C + ((c >> 3) ^ (tx & 7)) * 8 + (c & 7)] = f2bfu(xr[j]);
  }
  __syncthreads();
  // MFMA
  f32x4 dacc[MT];
#pragma unroll
  for (int mt = 0; mt < MT; ++mt) dacc[mt] = (f32x4){0.f, 0.f, 0.f, 0.f};
  int tr = w * 16 + lf;
#pragma unroll
  for (int kc = 0; kc < C / 32; ++kc) {
    int kg0 = kc * 4 + quad;
    bf16x8 bfr = *(const bf16x8*)(Is + tr * C + ((kg0 ^ (tr & 7)) * 8));
#pragma unroll
    for (int mt = 0; mt < MT; ++mt) {
      int o = mt * 16 + lf;
      bf16x8 afr = *(const bf16x8*)(Ws + o * C + ((kg0 ^ (o & 7)) * 8));
      dacc[mt] = __builtin_amdgcn_mfma_f32_16x16x32_bf16(afr, bfr, dacc[mt], 0, 0, 0);
    }
  }
  int tg = t0 + w * 16 + lf;
  if (tg < T) {
    long nb = (long)(b * N + n) * O;
#pragma unroll
    for (int mt = 0; mt < MT; ++mt) {
#pragma unroll
      for (int r = 0; r < 4; ++r) {
        int o = mt * 16 + quad * 4 + r;
        float v = dacc[mt][r] + bias[o];
        v = v > 0.f ? v : (expf(v) - 1.f);
        h[(nb + o) * T + tg] = __float2bfloat16(v);
      }
    }
  }
}

// ---------- MFMA pool GEMM: out[b,m,f] = sum_k Pb[m,k] * h[b,k,f] ----------
// BM = 64*WMT, BN = 16*FT
template<int WMT, int FT, typename TOut>
__global__ __launch_bounds__(256) void k_pool_mfma(const ushort_t* Pb, const ushort_t* h,
                                                   TOut* out, int M, int K, int F) {
  constexpr int BM = 64 * WMT;
  constexpr int BN = 16 * FT;
  __shared__ __align__(16) ushort_t As[BM * 64];
  __shared__ __align__(16) ushort_t Bs[BN * 64];
  int tid = threadIdx.x;
  int w = tid >> 6, l = tid & 63;
  int lf = l & 15, quad = l >> 4;
  int f0 = blockIdx.x * BN;
  int m0 = blockIdx.y * BM;
  int b = blockIdx.z;
  f32x4 acc[WMT][FT];
#pragma unroll
  for (int wt = 0; wt < WMT; ++wt)
#pragma unroll
    for (int ft = 0; ft < FT; ++ft) acc[wt][ft] = (f32x4){0.f, 0.f, 0.f, 0.f};

  for (int k0 = 0; k0 < K; k0 += 64) {
#pragma unroll
    for (int it = 0; it < BM / 32; ++it) {
      int cc = tid + 256 * it;
      int m = cc >> 3, kc = cc & 7;
      uint4 v = *(const uint4*)(Pb + (long)(m0 + m) * K + k0 + kc * 8);
      *(uint4*)(As + m * 64 + ((kc ^ (m & 7)) * 8)) = v;
    }
#pragma unroll
    for (int kb = (tid / BN) * 16; kb < 64; kb += (256 / BN) * 16) {
      int f = tid % BN;
      const ushort_t* hp = h + ((long)(b * K + k0 + kb)) * F + f0 + f;
      ushort_t r[16];
#pragma unroll
      for (int i = 0; i < 16; ++i) r[i] = hp[(long)i * F];
      int kc0 = kb >> 3;
      *(uint4*)(Bs + f * 64 + ((kc0 ^ (f & 7)) * 8)) = *(uint4*)&r[0];
      *(uint4*)(Bs + f * 64 + (((kc0 + 1) ^ (f & 7)) * 8)) = *(uint4*)&r[8];
    }
    __syncthreads();
#pragma unroll
    for (int ks = 0; ks < 2; ++ks) {
      int kc = ks * 4 + quad;
      bf16x8 bfr[FT];
#pragma unroll
      for (int ft = 0; ft < FT; ++ft) {
        int fl = ft * 16 + lf;
        bfr[ft] = *(const bf16x8*)(Bs + fl * 64 + ((kc ^ (fl & 7)) * 8));
      }
#pragma unroll
      for (int wt = 0; wt < WMT; ++wt) {
        int ml = wt * 64 + w * 16 + lf;
        bf16x8 afr = *(const bf16x8*)(As + ml * 64 + ((kc ^ (ml & 7)) * 8));
#pragma unroll
        for (int ft = 0; ft < FT; ++ft)
          acc[wt][ft] = __builtin_amdgcn_mfma_f32_16x16x32_bf16(afr, bfr[ft], acc[wt][ft], 0, 0, 0);
      }
    }
    __syncthreads();
  }
#pragma unroll
  for (int wt = 0; wt < WMT; ++wt) {
#pragma unroll
    for (int r = 0; r < 4; ++r) {
      int m = m0 + wt * 64 + w * 16 + quad * 4 + r;
      TOut* op = out + ((long)(b * M + m)) * F + f0 + lf;
#pragma unroll
      for (int ft = 0; ft < FT; ++ft)
        stf(op + ft * 16, acc[wt][ft][r]);
    }
  }
}

// ---------- fused head: hp3 fp32 [B][64][64][T] -> elu(W1) -> tanh(W2) -> d_out ----------
__global__ __launch_bounds__(256) void k_head(const float* hp3, const ushort_t* W1t,
    const ushort_t* W2t, const float* bias, void* outp, const int* flagp) {
  __shared__ __align__(16) ushort_t Ws1[128 * 64];
  __shared__ __align__(16) ushort_t Ws2[64 * 128];
  __shared__ __align__(16) ushort_t Is[64 * 64];
  __shared__ __align__(16) ushort_t G[64 * 128];
  int tid = threadIdx.x;
  int w = tid >> 6, l = tid & 63;
  int lf = l & 15, quad = l >> 4;
  int t0 = blockIdx.x * 64;
  int n = blockIdx.y, b = blockIdx.z;
  // stage W1t [128][64] and W2t [64][128]
  {
    const uint4* g1 = (const uint4*)W1t;
    for (int s = tid; s < 1024; s += 256) {
      int o = s >> 3, kg = s & 7;
      *(uint4*)(Ws1 + o * 64 + ((kg ^ (o & 7)) * 8)) = g1[s];
    }
    const uint4* g2 = (const uint4*)W2t;
    for (int s = tid; s < 1024; s += 256) {
      int o = s >> 4, kg = s & 15;
      *(uint4*)(Ws2 + o * 128 + ((kg ^ (o & 7)) * 8)) = g2[s];
    }
  }
  // stage Is [64t][64c] from hp3
  {
    int t = tid & 63;
    bool tok = (t0 + t) < T;
    const float* ip = hp3 + ((long)(b * 64 + n) * 64) * T + t0;
    for (int kg = tid >> 6; kg < 8; kg += 4) {
      ushort_t r[8];
#pragma unroll
      for (int j = 0; j < 8; ++j)
        r[j] = tok ? f2bfu(ip[(kg * 8 + j) * T + t]) : (ushort_t)0;
      *(uint4*)(Is + t * 64 + ((kg ^ (t & 7)) * 8)) = *(uint4*)r;
    }
  }
  __syncthreads();
  int tr = w * 16 + lf;
  // MFMA1: 64 -> 128, elu, into G
  {
    f32x4 a1[8];
#pragma unroll
    for (int mt = 0; mt < 8; ++mt) a1[mt] = (f32x4){0.f, 0.f, 0.f, 0.f};
#pragma unroll
    for (int kc = 0; kc < 2; ++kc) {
      int kg0 = kc * 4 + quad;
      bf16x8 bfr = *(const bf16x8*)(Is + tr * 64 + ((kg0 ^ (tr & 7)) * 8));
#pragma unroll
      for (int mt = 0; mt < 8; ++mt) {
        int o = mt * 16 + lf;
        bf16x8 afr = *(const bf16x8*)(Ws1 + o * 64 + ((kg0 ^ (o & 7)) * 8));
        a1[mt] = __builtin_amdgcn_mfma_f32_16x16x32_bf16(afr, bfr, a1[mt], 0, 0, 0);
      }
    }
    int tG = w * 16 + lf;
#pragma unroll
    for (int mt = 0; mt < 8; ++mt) {
#pragma unroll
      for (int r = 0; r < 4; ++r) {
        int o1 = mt * 16 + quad * 4 + r;
        float v = a1[mt][r] + bias[112 + o1];
        v = v > 0.f ? v : (expf(v) - 1.f);
        G[tG * 128 + ((o1 >> 3) ^ (tG & 7)) * 8 + (o1 & 7)] = f2bfu(v);
      }
    }
  }
  __syncthreads();
  // MFMA2: 128 -> 64, tanh, store
  {
    f32x4 a2[4];
#pragma unroll
    for (int mt = 0; mt < 4; ++mt) a2[mt] = (f32x4){0.f, 0.f, 0.f, 0.f};
#pragma unroll
    for (int kc = 0; kc < 4; ++kc) {
      int kg0 = kc * 4 + quad;
      bf16x8 bfr = *(const bf16x8*)(G + tr * 128 + ((kg0 ^ (tr & 7)) * 8));
#pragma unroll
      for (int mt = 0; mt < 4; ++mt) {
        int o = mt * 16 + lf;
        bf16x8 afr = *(const bf16x8*)(Ws2 + o * 128 + ((kg0 ^ (o & 7)) * 8));
        a2[mt] = __builtin_amdgcn_mfma_f32_16x16x32_bf16(afr, bfr, a2[mt], 0, 0, 0);
      }
    }
    int t = t0 + w * 16 + lf;
    if (t < T) {
      int bf = *flagp;
      long nb = (long)(b * 64 + n) * 64;
#pragma unroll
      for (int mt = 0; mt < 4; ++mt) {
#pragma unroll
        for (int r = 0; r < 4; ++r) {
          int o2 = mt * 16 + quad * 4 + r;
          float v = tanhf(a2[mt][r] + bias[240 + o2]);
          long idx = (nb + o2) * T + t;
          if (bf) ((bf16*)outp)[idx] = __float2bfloat16(v);
          else    ((float*)outp)[idx] = v;
        }
      }
    }
  }
}

extern "C" void kernel_launch(void* const* d_in, const int* in_sizes, int n_in,
                              void* d_out, int out_size, void* d_ws, size_t ws_size,
                              hipStream_t stream) {
  const int* ei0 = (const int*)d_in[1];
  const int* ei1 = (const int*)d_in[3];
  const int* ei2 = (const int*)d_in[5];

  char* base = (char*)d_ws;
  int* I = (int*)base;
  int* cnt0 = I;         int* off0 = I + 2048;  int* cur0 = I + 4112;  int* el0 = I + 6160;
  int* cnt1 = I + 22544; int* off1 = I + 23056; int* cur1 = I + 23584; int* el1 = I + 24096;
  int* cnt2 = I + 32288; int* off2 = I + 32416; int* cur2 = I + 32560; int* el2 = I + 32688;
  const int* flagp = (const int*)(base + O_FLAG);
  float* wc1f = (float*)(base + O_WC1);
  float* bias = (float*)(base + O_BIAS);
  float* bw0 = (float*)(base + O_BW0);
  float* bw1 = (float*)(base + O_BW1);
  float* bw2 = (float*)(base + O_BW2);
  ushort_t* Pb1 = (ushort_t*)(base + O_PB1);
  ushort_t* Pb2 = (ushort_t*)(base + O_PB2);
  ushort_t* Pb3 = (ushort_t*)(base + O_PB3);
  ushort_t* wt2 = (ushort_t*)(base + O_WT2);
  ushort_t* wt3 = (ushort_t*)(base + O_WT3);
  ushort_t* w1t = (ushort_t*)(base + O_W1H);
  ushort_t* w2t = (ushort_t*)(base + O_W2H);
  char* Aa = base + O_AA;
  char* Bb = base + O_BB;

  InPtrs P = { d_in[2], d_in[4], d_in[6], d_in[19], d_in[20], d_in[21],
               d_in[8], d_in[9], d_in[12], d_in[13], d_in[16], d_in[17],
               d_in[22], d_in[24], d_in[10], d_in[14], d_in[18], d_in[23],
               d_in[25], d_in[7], d_in[11], d_in[15] };

  k_setup0<<<159, 256, 0, stream>>>(I, (const ushort_t*)d_in[2]);
  k_prep<<<4594, 256, 0, stream>>>(P, base);
  k_hist3<<<64, 256, 0, stream>>>(ei0 + E0, ei1 + E1, ei2 + E2, cnt0, cnt1, cnt2);
  k_scan3<<<3, 64, 0, stream>>>(cnt0, off0, cur0, cnt1, off1, cur1, cnt2, off2, cur2);
  k_fill3<<<64, 256, 0, stream>>>(ei0 + E0, cur0, el0, ei1 + E1, cur1, el1, ei2 + E2, cur2, el2);

  // level 0 -> 1: h1 bf16 (Bb), pool1 -> hp1 fp32 (Aa)
  k_gc1<<<dim3(1, N0, B), 256, 0, stream>>>(d_in[0], ei0, off0, el0, cnt0, bw0, wc1f, bias, (bf16*)Bb, flagp);
  k_pool_mfma<1, 4, float><<<dim3(50, 8, B), 256, 0, stream>>>(Pb1, (const ushort_t*)Bb, (float*)Aa, 512, 2048, 3200);
  // level 1 -> 2: fused gather+cmix -> h2 bf16 (Bb), pool2 -> hp2 fp32 (Aa)
  k_gcm<16, 4, 32><<<dim3(4, N1, B), 256, 0, stream>>>((const float*)Aa, ei1, off1, el1, cnt1, bw1, wt2, bias + 16, (bf16*)Bb, N1);
  k_pool_mfma<1, 4, float><<<dim3(100, 2, B), 256, 0, stream>>>(Pb2, (const ushort_t*)Bb, (float*)Aa, 128, 512, 6400);
  // level 2 -> 3: fused gather+cmix -> h3 bf16 (Bb), pool3 -> hp3 fp32 (Aa)
  k_gcm<32, 8, 64><<<dim3(4, N2, B), 256, 0, stream>>>((const float*)Aa, ei2, off2, el2, cnt2, bw2, wt3, bias + 48, (bf16*)Bb, N2);
  k_pool_mfma<1, 4, float><<<dim3(200, 1, B), 256, 0, stream>>>(Pb3, (const ushort_t*)Bb, (float*)Aa, 64, 128, 12800);
  // fused head -> d_out
  k_head<<<dim3(4, N3, B), 256, 0, stream>>>((const float*)Aa, w1t, w2t, bias, d_out, flagp);
}